// Round 2
// baseline (175.961 us; speedup 1.0000x reference)
//
#include <hip/hip_runtime.h>

// MACD: EMA_slow(x) - EMA_fast(x) over time axis.
// x: [B=4096, T=2048, F=8] fp32 contiguous. Block per b, thread per 8-step
// t-chunk (all 8 features). Chunk carries composed by an 8-step Kogge-Stone
// scan across the 256 threads (constant per-step multiplier D^(2^k)).

#define T_LEN 2048
#define FDIM 8
#define CHUNK 8
#define NCHUNK (T_LEN / CHUNK)   // 256 == blockDim.x
#define NSER (2 * FDIM)          // 16 series: (f, slow/fast)

__device__ __forceinline__ float pow8(float v) {
    float v2 = v * v;
    float v4 = v2 * v2;
    return v4 * v4;
}

__global__ __launch_bounds__(NCHUNK, 4)
void macd_kernel(const float* __restrict__ x, float* __restrict__ out) {
    const float AS  = (float)(2.0 / 27.0);   // alpha slow (N=26)
    const float AF  = (float)(2.0 / 13.0);   // alpha fast (N=12)
    const float OMS = 1.0f - AS;
    const float OMF = 1.0f - AF;

    const int b = blockIdx.x;
    const int c = threadIdx.x;               // chunk index 0..255

    const float* xb = x   + (size_t)b * (T_LEN * FDIM);
    float*       ob = out + (size_t)b * (T_LEN * FDIM);

    // ---------------- Phase 1: local zero-init EMAs, diffs stay in regs ----
    float p[NSER];                            // p[2f]=slow, p[2f+1]=fast
    float diff[CHUNK][FDIM];
#pragma unroll
    for (int s = 0; s < NSER; ++s) p[s] = 0.f;

    const float4* xv = reinterpret_cast<const float4*>(xb + c * CHUNK * FDIM);
#pragma unroll
    for (int i = 0; i < CHUNK; ++i) {
        float4 lo = xv[i * 2 + 0];
        float4 hi = xv[i * 2 + 1];
        float xx[FDIM] = {lo.x, lo.y, lo.z, lo.w, hi.x, hi.y, hi.z, hi.w};
#pragma unroll
        for (int f = 0; f < FDIM; ++f) {
            p[2 * f + 0] = AS * xx[f] + OMS * p[2 * f + 0];
            p[2 * f + 1] = AF * xx[f] + OMF * p[2 * f + 1];
            diff[i][f] = p[2 * f + 0] - p[2 * f + 1];
        }
    }

    // Seed y_{-1} = x0 into chunk 0's partial (gives exact y0 = x0 chain).
    {
        const float DS = pow8(OMS), DF = pow8(OMF);
        if (c == 0) {
#pragma unroll
            for (int f = 0; f < FDIM; ++f) {
                float x0 = xb[f];             // L1 hit (just loaded)
                p[2 * f + 0] += DS * x0;
                p[2 * f + 1] += DF * x0;
            }
        }
    }

    // ---------------- Kogge-Stone inclusive scan over 256 chunks -----------
    // p[c] += D^(2^k) * p[c - 2^k]; multipliers fold to compile-time consts.
    __shared__ float sc[NSER][NCHUNK];        // 16 KiB; stride-1 across lanes
    float Ms = pow8(OMS), Mf = pow8(OMF);
#pragma unroll
    for (int off = 1; off < NCHUNK; off <<= 1) {
#pragma unroll
        for (int s = 0; s < NSER; ++s) sc[s][c] = p[s];
        __syncthreads();
        if (c >= off) {
#pragma unroll
            for (int s = 0; s < NSER; ++s)
                p[s] += ((s & 1) ? Mf : Ms) * sc[s][c - off];
        }
        Ms *= Ms; Mf *= Mf;
        __syncthreads();
    }
#pragma unroll
    for (int s = 0; s < NSER; ++s) sc[s][c] = p[s];
    __syncthreads();

    // Exclusive carry-in for chunk c (chunk 0's carry-in is x0 itself).
    float ws[FDIM], wf[FDIM];
#pragma unroll
    for (int f = 0; f < FDIM; ++f) {
        float cs, cf;
        if (c == 0) { cs = cf = xb[f]; }
        else        { cs = sc[2 * f + 0][c - 1]; cf = sc[2 * f + 1][c - 1]; }
        ws[f] = OMS * cs;                      // om_s^1 * carry_slow
        wf[f] = OMF * cf;                      // om_f^1 * carry_fast
    }

    // ---------------- Phase 2: add geometric corrections, write out --------
    float4* ov = reinterpret_cast<float4*>(ob + c * CHUNK * FDIM);
#pragma unroll
    for (int i = 0; i < CHUNK; ++i) {
        float o[FDIM];
#pragma unroll
        for (int f = 0; f < FDIM; ++f) {
            o[f] = diff[i][f] + (ws[f] - wf[f]);
            ws[f] *= OMS;
            wf[f] *= OMF;
        }
        float4 lo = {o[0], o[1], o[2], o[3]};
        float4 hi = {o[4], o[5], o[6], o[7]};
        ov[i * 2 + 0] = lo;
        ov[i * 2 + 1] = hi;
    }
}

extern "C" void kernel_launch(void* const* d_in, const int* in_sizes, int n_in,
                              void* d_out, int out_size, void* d_ws, size_t ws_size,
                              hipStream_t stream) {
    (void)n_in; (void)d_ws; (void)ws_size; (void)out_size;
    const float* x = (const float*)d_in[0];
    float* out = (float*)d_out;
    const int B = in_sizes[0] / (T_LEN * FDIM);   // 4096
    macd_kernel<<<dim3(B), dim3(NCHUNK), 0, stream>>>(x, out);
}